// Round 1
// baseline (747.619 us; speedup 1.0000x reference)
//
#include <hip/hip_runtime.h>

namespace {
constexpr int kB    = 8192;
constexpr int kNB   = 64;
constexpr int kF    = 256;
constexpr int kK    = 8;
constexpr int kKS   = 5;
constexpr int kH    = 256;
constexpr int kOUT  = 128;
constexpr int kXRows = kK + 1;            // 9
constexpr int kTOut  = kXRows - kKS + 1;  // 5
}

__global__ __launch_bounds__(256)
void lgc_fused(const int* __restrict__ node_ids,
               const int* __restrict__ neighbors,
               const float* __restrict__ feat,
               const float* __restrict__ W1,
               const float* __restrict__ b1,
               const float* __restrict__ W2,
               const float* __restrict__ b2,
               float* __restrict__ out)
{
  // x stored [channel][row]: row-stride 9 floats -> gcd(9,32)=1, conflict-free
  // column writes; reads are wave-uniform broadcasts (free).
  __shared__ float x_lds[kF][kXRows];
  __shared__ float h_lds[kTOut][kH];

  const int b   = blockIdx.x;
  const int tid = threadIdx.x;

  // ---------------- gather + per-channel top-8 ----------------
  {
    const int f = tid;  // 256 threads == kF channels
    const long long nrow = (long long)node_ids[b];

    float tk[kK];
#pragma unroll
    for (int k = 0; k < kK; ++k) tk[k] = -INFINITY;

    const int* nbp = neighbors + (long long)b * kNB;
    for (int n = 0; n < kNB; ++n) {
      const long long r = (long long)nbp[n];       // uniform -> s_load
      const float v = feat[r * kF + f];            // coalesced 1KB row read
      // branchless sorted insert: only tk[7] can be out of order, one
      // bottom-to-top compare-exchange pass restores descending order.
      tk[kK - 1] = fmaxf(tk[kK - 1], v);
#pragma unroll
      for (int k = kK - 1; k > 0; --k) {
        const float hi = fmaxf(tk[k - 1], tk[k]);
        const float lo = fminf(tk[k - 1], tk[k]);
        tk[k - 1] = hi;
        tk[k]     = lo;
      }
    }

    x_lds[f][0] = feat[nrow * kF + f];
#pragma unroll
    for (int k = 0; k < kK; ++k) x_lds[f][1 + k] = tk[k];
  }
  __syncthreads();

  // ---------------- conv1: h[t][hc], t = 0..4 ----------------
  {
    const int hc = tid;
    float acc[kTOut];
#pragma unroll
    for (int t = 0; t < kTOut; ++t) acc[t] = b1[hc];

    for (int f = 0; f < kF; ++f) {
      float xv[kXRows];
#pragma unroll
      for (int r = 0; r < kXRows; ++r) xv[r] = x_lds[f][r];  // broadcast reads
#pragma unroll
      for (int dt = 0; dt < kKS; ++dt) {
        const float w = W1[((dt * kF) + f) * kH + hc];       // coalesced, L2-hot
#pragma unroll
        for (int t = 0; t < kTOut; ++t)
          acc[t] = fmaf(xv[dt + t], w, acc[t]);
      }
    }
#pragma unroll
    for (int t = 0; t < kTOut; ++t) h_lds[t][hc] = acc[t];
  }
  __syncthreads();

  // ---------------- conv2: out[b][o] ----------------
  if (tid < kOUT) {
    const int o = tid;
    float acc = b2[o];
#pragma unroll
    for (int dt = 0; dt < kKS; ++dt) {
      for (int hc = 0; hc < kH; ++hc) {
        acc = fmaf(h_lds[dt][hc], W2[((dt * kH) + hc) * kOUT + o], acc);
      }
    }
    out[(long long)b * kOUT + o] = acc;
  }
}

extern "C" void kernel_launch(void* const* d_in, const int* in_sizes, int n_in,
                              void* d_out, int out_size, void* d_ws, size_t ws_size,
                              hipStream_t stream) {
  const int*   node_ids  = (const int*)  d_in[0];
  const int*   neighbors = (const int*)  d_in[1];
  const float* feat      = (const float*)d_in[2];
  const float* W1        = (const float*)d_in[3];
  const float* b1        = (const float*)d_in[4];
  const float* W2        = (const float*)d_in[5];
  const float* b2        = (const float*)d_in[6];
  float* out = (float*)d_out;

  lgc_fused<<<kB, 256, 0, stream>>>(node_ids, neighbors, feat, W1, b1, W2, b2, out);
}

// Round 2
// 192.668 us; speedup vs baseline: 3.8803x; 3.8803x over previous
//
#include <hip/hip_runtime.h>
#include <hip/hip_bf16.h>

namespace {
constexpr int kB    = 8192;
constexpr int kNB   = 64;
constexpr int kF    = 256;
constexpr int kK    = 8;
constexpr int kKS   = 5;
constexpr int kH    = 256;
constexpr int kOUT  = 128;
constexpr int kXR   = 9;   // x rows (1 node + 8 topk)
constexpr int kTO   = 5;   // conv1 output positions

// workspace layout (bytes)
constexpr size_t X_OFF   = 0;                                   // bf16 [B][9][256]
constexpr size_t W1T_OFF = (size_t)kB * kXR * kF * 2;           // bf16 [5][256(hc)][256(f)]
constexpr size_t W2T_OFF = W1T_OFF + (size_t)kKS * kH * kF * 2; // bf16 [128(o)][1280(k)]

typedef __attribute__((ext_vector_type(8))) short short8; // 8 bf16 (A/B frag)
typedef __attribute__((ext_vector_type(4))) float f32x4;  // C/D frag
}

using bf16 = __hip_bfloat16;

// ---------------- kernel 1: weight convert/transpose to bf16 ----------------
__global__ void convert_weights(const float* __restrict__ W1,
                                const float* __restrict__ W2,
                                bf16* __restrict__ w1t, bf16* __restrict__ w2t)
{
  const int i = blockIdx.x * 256 + threadIdx.x;
  const int stride = gridDim.x * 256;
  // W1T[dt][hc][f] = W1[dt][f][hc]
  for (int idx = i; idx < kKS * kH * kF; idx += stride) {
    const int f  = idx & 255;
    const int hc = (idx >> 8) & 255;
    const int dt = idx >> 16;
    w1t[idx] = __float2bfloat16(W1[(dt * kF + f) * kH + hc]);
  }
  // W2T[o][dt*256+hc] = W2[dt][hc][o]
  for (int idx = i; idx < kOUT * kKS * kH; idx += stride) {
    const int k = idx % (kKS * kH);
    const int o = idx / (kKS * kH);
    w2t[idx] = __float2bfloat16(W2[k * kOUT + o]);
  }
}

// ---------------- kernel 2: gather + per-channel top-8 -> x (bf16) ----------------
__global__ __launch_bounds__(256)
void gather_topk(const int* __restrict__ node_ids,
                 const int* __restrict__ neighbors,
                 const float* __restrict__ feat,
                 bf16* __restrict__ x)
{
  const int b = blockIdx.x;
  const int f = threadIdx.x;
  const long long nrow = (long long)node_ids[b];

  float tk[kK];
#pragma unroll
  for (int k = 0; k < kK; ++k) tk[k] = -INFINITY;

  const int* nbp = neighbors + (long long)b * kNB;
  for (int n = 0; n < kNB; ++n) {
    const long long r = (long long)nbp[n];
    const float v = feat[r * kF + f];
    tk[kK - 1] = fmaxf(tk[kK - 1], v);
#pragma unroll
    for (int k = kK - 1; k > 0; --k) {
      const float hi = fmaxf(tk[k - 1], tk[k]);
      const float lo = fminf(tk[k - 1], tk[k]);
      tk[k - 1] = hi;
      tk[k]     = lo;
    }
  }

  bf16* xb = x + (size_t)b * kXR * kF;
  xb[f] = __float2bfloat16(feat[nrow * kF + f]);
#pragma unroll
  for (int k = 0; k < kK; ++k) xb[(1 + k) * kF + f] = __float2bfloat16(tk[k]);
}

// ---------------- kernel 3: conv1+conv2 via MFMA ----------------
__global__ __launch_bounds__(256)
void conv_gemm(const bf16* __restrict__ x, const bf16* __restrict__ w1t,
               const bf16* __restrict__ w2t, const float* __restrict__ b1,
               const float* __restrict__ b2, float* __restrict__ out)
{
  constexpr int BM   = 16;
  constexpr int XPAD = 264;   // x inner stride (bf16): b-stride = 9*264 elems = 1188 dwords ≡ 4 mod 32 -> 2-way (free)
  constexpr int HPAD = 1288;  // h row stride (bf16): 644 dwords ≡ 4 mod 32 -> 2-way (free)

  __shared__ bf16 smem[BM * kXR * XPAD];  // 38016 bf16 = 76 KB; reused for h (16*1288=20608)
  bf16* xs = smem;
  bf16* hs = smem;

  const int tid  = threadIdx.x;
  const int wave = tid >> 6;
  const int lane = tid & 63;
  const int r = lane & 15;   // tile row/col-within
  const int q = lane >> 4;   // quarter
  const int bbase = blockIdx.x * BM;

  // ---- stage x tile [16][9][256] -> padded LDS ----
  {
    const bf16* gx = x + (size_t)bbase * kXR * kF;
    for (int c = tid; c < BM * kXR * (kF / 8); c += 256) {  // 4608 chunks of 8 bf16
      const int f8  = c & 31;
      const int row = (c >> 5) % kXR;
      const int bb  = c / (32 * kXR);
      short8 v = *reinterpret_cast<const short8*>(gx + (size_t)c * 8);
      *reinterpret_cast<short8*>(&xs[(bb * kXR + row) * XPAD + f8 * 8]) = v;
    }
  }
  __syncthreads();

  // ---- GEMM1: h[b][t][hc] = sum_dt,f x[b][t+dt][f] * W1[dt][f][hc] + b1 ----
  const int ntb = wave * 64;  // this wave's hc base (4 n-tiles of 16)
  f32x4 acc[kTO][4];
#pragma unroll
  for (int n = 0; n < 4; ++n) {
    const float bv = b1[ntb + n * 16 + r];
#pragma unroll
    for (int m = 0; m < kTO; ++m) acc[m][n] = (f32x4){bv, bv, bv, bv};
  }

  for (int kk = 0; kk < 8; ++kk) {         // K within dt: 8 steps of 32
    short8 a[kXR];
#pragma unroll
    for (int rr = 0; rr < kXR; ++rr)
      a[rr] = *reinterpret_cast<const short8*>(&xs[(r * kXR + rr) * XPAD + kk * 32 + q * 8]);
#pragma unroll
    for (int dt = 0; dt < kKS; ++dt) {
      short8 bfr[4];
#pragma unroll
      for (int n = 0; n < 4; ++n)
        bfr[n] = *reinterpret_cast<const short8*>(
            &w1t[((size_t)(dt * kH + ntb + n * 16 + r)) * kF + kk * 32 + q * 8]);
#pragma unroll
      for (int m = 0; m < kTO; ++m)
#pragma unroll
        for (int n = 0; n < 4; ++n)
          acc[m][n] = __builtin_amdgcn_mfma_f32_16x16x32_bf16(a[m + dt], bfr[n], acc[m][n], 0, 0, 0);
    }
  }
  __syncthreads();  // all waves done reading xs; safe to overwrite with h

  // ---- write h (bf16) into LDS: hs[b][t*256 + hc] ----
  // C/D layout: col = lane&15 (hc), row = q*4+j (b)
#pragma unroll
  for (int m = 0; m < kTO; ++m)
#pragma unroll
    for (int n = 0; n < 4; ++n)
#pragma unroll
      for (int j = 0; j < 4; ++j)
        hs[(q * 4 + j) * HPAD + m * kH + ntb + n * 16 + r] = __float2bfloat16(acc[m][n][j]);
  __syncthreads();

  // ---- GEMM2: out[b][o] = sum_k h[b][k] * W2T[o][k] + b2 ----
  const int ob = wave * 32;  // this wave's o base (2 n-tiles of 16)
  f32x4 acc2[2];
#pragma unroll
  for (int n = 0; n < 2; ++n) {
    const float bv = b2[ob + n * 16 + r];
    acc2[n] = (f32x4){bv, bv, bv, bv};
  }
  for (int ks = 0; ks < 40; ++ks) {
    short8 a2 = *reinterpret_cast<const short8*>(&hs[r * HPAD + ks * 32 + q * 8]);
#pragma unroll
    for (int n = 0; n < 2; ++n) {
      short8 b2f = *reinterpret_cast<const short8*>(
          &w2t[(size_t)(ob + n * 16 + r) * (kKS * kH) + ks * 32 + q * 8]);
      acc2[n] = __builtin_amdgcn_mfma_f32_16x16x32_bf16(a2, b2f, acc2[n], 0, 0, 0);
    }
  }
#pragma unroll
  for (int n = 0; n < 2; ++n)
#pragma unroll
    for (int j = 0; j < 4; ++j)
      out[(size_t)(bbase + q * 4 + j) * kOUT + ob + n * 16 + r] = acc2[n][j];
}

extern "C" void kernel_launch(void* const* d_in, const int* in_sizes, int n_in,
                              void* d_out, int out_size, void* d_ws, size_t ws_size,
                              hipStream_t stream) {
  const int*   node_ids  = (const int*)  d_in[0];
  const int*   neighbors = (const int*)  d_in[1];
  const float* feat      = (const float*)d_in[2];
  const float* W1        = (const float*)d_in[3];
  const float* b1        = (const float*)d_in[4];
  const float* W2        = (const float*)d_in[5];
  const float* b2        = (const float*)d_in[6];
  float* out = (float*)d_out;

  char* ws = (char*)d_ws;
  bf16* x_ws  = (bf16*)(ws + X_OFF);
  bf16* w1t   = (bf16*)(ws + W1T_OFF);
  bf16* w2t   = (bf16*)(ws + W2T_OFF);

  convert_weights<<<512, 256, 0, stream>>>(W1, W2, w1t, w2t);
  gather_topk<<<kB, 256, 0, stream>>>(node_ids, neighbors, feat, x_ws);
  conv_gemm<<<kB / 16, 256, 0, stream>>>(x_ws, w1t, w2t, b1, b2, out);
}

// Round 3
// 168.611 us; speedup vs baseline: 4.4340x; 1.1427x over previous
//
#include <hip/hip_runtime.h>
#include <hip/hip_bf16.h>

namespace {
constexpr int kB    = 8192;
constexpr int kNB   = 64;
constexpr int kF    = 256;
constexpr int kK    = 8;
constexpr int kKS   = 5;
constexpr int kH    = 256;
constexpr int kOUT  = 128;
constexpr int kXR   = 9;   // x rows (1 node + 8 topk)
constexpr int kTO   = 5;   // conv1 output positions

// workspace layout (bytes)
constexpr size_t X_OFF   = 0;                                   // bf16 [B][9][256]
constexpr size_t W1T_OFF = (size_t)kB * kXR * kF * 2;           // bf16 [5][256(hc)][256(f)]
constexpr size_t W2T_OFF = W1T_OFF + (size_t)kKS * kH * kF * 2; // bf16 [128(o)][1280(k)]

typedef __attribute__((ext_vector_type(8))) short short8; // 8 bf16 (A/B frag)
typedef __attribute__((ext_vector_type(4))) float f32x4;  // C/D frag
}

using bf16 = __hip_bfloat16;

__device__ __forceinline__ unsigned short f2bf(float f) {
  bf16 h = __float2bfloat16(f);
  return *reinterpret_cast<unsigned short*>(&h);
}

// ---------------- kernel 1: weight convert/transpose to bf16 ----------------
__global__ void convert_weights(const float* __restrict__ W1,
                                const float* __restrict__ W2,
                                bf16* __restrict__ w1t, bf16* __restrict__ w2t)
{
  const int i = blockIdx.x * 256 + threadIdx.x;
  const int stride = gridDim.x * 256;
  // W1T[dt][hc][f] = W1[dt][f][hc]
  for (int idx = i; idx < kKS * kH * kF; idx += stride) {
    const int f  = idx & 255;
    const int hc = (idx >> 8) & 255;
    const int dt = idx >> 16;
    w1t[idx] = __float2bfloat16(W1[(dt * kF + f) * kH + hc]);
  }
  // W2T[o][dt*256+hc] = W2[dt][hc][o]
  for (int idx = i; idx < kOUT * kKS * kH; idx += stride) {
    const int k = idx % (kKS * kH);
    const int o = idx / (kKS * kH);
    w2t[idx] = __float2bfloat16(W2[k * kOUT + o]);
  }
}

// ---------------- kernel 2: gather + per-channel top-8 -> x (bf16) ----------------
// One WAVE per batch element; each lane owns 4 channels (float4 loads).
// Neighbor ids distributed one-per-lane, broadcast via readlane -> SGPR
// row addressing. 4 independent top-8 chains per thread hide CE latency.
__global__ __launch_bounds__(256)
void gather_topk(const int* __restrict__ node_ids,
                 const int* __restrict__ neighbors,
                 const float* __restrict__ feat,
                 bf16* __restrict__ x)
{
  const int wave = threadIdx.x >> 6;
  const int lane = threadIdx.x & 63;
  const int b    = blockIdx.x * 4 + wave;
  const int f4   = lane << 2;

  const int myn = neighbors[(size_t)b * kNB + lane];  // one neighbor id per lane
  const int nid = node_ids[b];

  const float4 nodev =
      *reinterpret_cast<const float4*>(feat + (size_t)nid * kF + f4);

  float tk[4][kK];
#pragma unroll
  for (int c = 0; c < 4; ++c)
#pragma unroll
    for (int k = 0; k < kK; ++k) tk[c][k] = -INFINITY;

#pragma unroll 16
  for (int n = 0; n < kNB; ++n) {
    const int r = __builtin_amdgcn_readlane(myn, n);   // SGPR row id
    const float4 v =
        *reinterpret_cast<const float4*>(feat + (size_t)r * kF + f4);
    const float vv[4] = {v.x, v.y, v.z, v.w};
#pragma unroll
    for (int c = 0; c < 4; ++c) {
      // branchless sorted insert (descending); 4 independent chains
      tk[c][kK - 1] = fmaxf(tk[c][kK - 1], vv[c]);
#pragma unroll
      for (int k = kK - 1; k > 0; --k) {
        const float hi = fmaxf(tk[c][k - 1], tk[c][k]);
        const float lo = fminf(tk[c][k - 1], tk[c][k]);
        tk[c][k - 1] = hi;
        tk[c][k]     = lo;
      }
    }
  }

  bf16* xb = x + (size_t)b * kXR * kF + f4;
  {
    ushort4 s = {f2bf(nodev.x), f2bf(nodev.y), f2bf(nodev.z), f2bf(nodev.w)};
    *reinterpret_cast<ushort4*>(xb) = s;
  }
#pragma unroll
  for (int k = 0; k < kK; ++k) {
    ushort4 s = {f2bf(tk[0][k]), f2bf(tk[1][k]), f2bf(tk[2][k]), f2bf(tk[3][k])};
    *reinterpret_cast<ushort4*>(xb + (size_t)(1 + k) * kF) = s;
  }
}

// ---------------- kernel 3: conv1+conv2 via MFMA ----------------
__global__ __launch_bounds__(256)
void conv_gemm(const bf16* __restrict__ x, const bf16* __restrict__ w1t,
               const bf16* __restrict__ w2t, const float* __restrict__ b1,
               const float* __restrict__ b2, float* __restrict__ out)
{
  constexpr int BM   = 16;
  constexpr int XPAD = 264;   // x inner stride (bf16): 2-way bank alias only (free)
  constexpr int HPAD = 1288;  // h row stride (bf16): 2-way alias (free)

  __shared__ bf16 smem[BM * kXR * XPAD];  // 76 KB; reused for h
  bf16* xs = smem;
  bf16* hs = smem;

  const int tid  = threadIdx.x;
  const int wave = tid >> 6;
  const int lane = tid & 63;
  const int r = lane & 15;
  const int q = lane >> 4;
  const int bbase = blockIdx.x * BM;

  // ---- stage x tile [16][9][256] -> padded LDS ----
  {
    const bf16* gx = x + (size_t)bbase * kXR * kF;
    for (int c = tid; c < BM * kXR * (kF / 8); c += 256) {
      const int f8  = c & 31;
      const int row = (c >> 5) % kXR;
      const int bb  = c / (32 * kXR);
      short8 v = *reinterpret_cast<const short8*>(gx + (size_t)c * 8);
      *reinterpret_cast<short8*>(&xs[(bb * kXR + row) * XPAD + f8 * 8]) = v;
    }
  }
  __syncthreads();

  // ---- GEMM1: h[b][t][hc] = sum_dt,f x[b][t+dt][f] * W1[dt][f][hc] + b1 ----
  const int ntb = wave * 64;
  f32x4 acc[kTO][4];
#pragma unroll
  for (int n = 0; n < 4; ++n) {
    const float bv = b1[ntb + n * 16 + r];
#pragma unroll
    for (int m = 0; m < kTO; ++m) acc[m][n] = (f32x4){bv, bv, bv, bv};
  }

  for (int kk = 0; kk < 8; ++kk) {
    short8 a[kXR];
#pragma unroll
    for (int rr = 0; rr < kXR; ++rr)
      a[rr] = *reinterpret_cast<const short8*>(&xs[(r * kXR + rr) * XPAD + kk * 32 + q * 8]);
#pragma unroll
    for (int dt = 0; dt < kKS; ++dt) {
      short8 bfr[4];
#pragma unroll
      for (int n = 0; n < 4; ++n)
        bfr[n] = *reinterpret_cast<const short8*>(
            &w1t[((size_t)(dt * kH + ntb + n * 16 + r)) * kF + kk * 32 + q * 8]);
#pragma unroll
      for (int m = 0; m < kTO; ++m)
#pragma unroll
        for (int n = 0; n < 4; ++n)
          acc[m][n] = __builtin_amdgcn_mfma_f32_16x16x32_bf16(a[m + dt], bfr[n], acc[m][n], 0, 0, 0);
    }
  }
  __syncthreads();

  // ---- write h (bf16) into LDS: hs[b][t*256 + hc] ----
#pragma unroll
  for (int m = 0; m < kTO; ++m)
#pragma unroll
    for (int n = 0; n < 4; ++n)
#pragma unroll
      for (int j = 0; j < 4; ++j)
        hs[(q * 4 + j) * HPAD + m * kH + ntb + n * 16 + r] = __float2bfloat16(acc[m][n][j]);
  __syncthreads();

  // ---- GEMM2: out[b][o] = sum_k h[b][k] * W2T[o][k] + b2 ----
  const int ob = wave * 32;
  f32x4 acc2[2];
#pragma unroll
  for (int n = 0; n < 2; ++n) {
    const float bv = b2[ob + n * 16 + r];
    acc2[n] = (f32x4){bv, bv, bv, bv};
  }
  for (int ks = 0; ks < 40; ++ks) {
    short8 a2 = *reinterpret_cast<const short8*>(&hs[r * HPAD + ks * 32 + q * 8]);
#pragma unroll
    for (int n = 0; n < 2; ++n) {
      short8 b2f = *reinterpret_cast<const short8*>(
          &w2t[(size_t)(ob + n * 16 + r) * (kKS * kH) + ks * 32 + q * 8]);
      acc2[n] = __builtin_amdgcn_mfma_f32_16x16x32_bf16(a2, b2f, acc2[n], 0, 0, 0);
    }
  }
#pragma unroll
  for (int n = 0; n < 2; ++n)
#pragma unroll
    for (int j = 0; j < 4; ++j)
      out[(size_t)(bbase + q * 4 + j) * kOUT + ob + n * 16 + r] = acc2[n][j];
}

extern "C" void kernel_launch(void* const* d_in, const int* in_sizes, int n_in,
                              void* d_out, int out_size, void* d_ws, size_t ws_size,
                              hipStream_t stream) {
  const int*   node_ids  = (const int*)  d_in[0];
  const int*   neighbors = (const int*)  d_in[1];
  const float* feat      = (const float*)d_in[2];
  const float* W1        = (const float*)d_in[3];
  const float* b1        = (const float*)d_in[4];
  const float* W2        = (const float*)d_in[5];
  const float* b2        = (const float*)d_in[6];
  float* out = (float*)d_out;

  char* ws = (char*)d_ws;
  bf16* x_ws  = (bf16*)(ws + X_OFF);
  bf16* w1t   = (bf16*)(ws + W1T_OFF);
  bf16* w2t   = (bf16*)(ws + W2T_OFF);

  convert_weights<<<512, 256, 0, stream>>>(W1, W2, w1t, w2t);
  gather_topk<<<kB / 4, 256, 0, stream>>>(node_ids, neighbors, feat, x_ws);
  conv_gemm<<<kB / 16, 256, 0, stream>>>(x_ws, w1t, w2t, b1, b2, out);
}

// Round 4
// 139.133 us; speedup vs baseline: 5.3734x; 1.2119x over previous
//
#include <hip/hip_runtime.h>
#include <hip/hip_bf16.h>

namespace {
constexpr int kB    = 8192;
constexpr int kNB   = 64;
constexpr int kF    = 256;
constexpr int kK    = 8;
constexpr int kKS   = 5;
constexpr int kH    = 256;
constexpr int kOUT  = 128;
constexpr int kXR   = 9;   // x rows (1 node + 8 topk)
constexpr int kTO   = 5;   // conv1 output positions
constexpr int kBM   = 16;  // batch rows per block

constexpr int XPAD = 258;   // r-stride = 9*129 dwords ≡ 9 (odd) mod 32 -> ≤2-way alias (free)
constexpr int HPAD = 1290;  // row stride 645 dwords ≡ 5 (odd) mod 32 -> ≤2-way alias (free)

// workspace layout (bytes)
constexpr size_t W1T_OFF = 0;                                   // bf16 [5][256(hc)][256(f)]
constexpr size_t W2T_OFF = W1T_OFF + (size_t)kKS * kH * kF * 2; // bf16 [128(o)][1280(k)]

typedef __attribute__((ext_vector_type(8))) short short8; // 8 bf16 (A/B frag)
typedef __attribute__((ext_vector_type(4))) float f32x4;  // C/D frag
}

using bf16 = __hip_bfloat16;

__device__ __forceinline__ unsigned short f2bf(float f) {
  bf16 h = __float2bfloat16(f);
  return *reinterpret_cast<unsigned short*>(&h);
}

// ---------------- kernel 1: weight convert/transpose to bf16 ----------------
__global__ void convert_weights(const float* __restrict__ W1,
                                const float* __restrict__ W2,
                                bf16* __restrict__ w1t, bf16* __restrict__ w2t)
{
  const int i = blockIdx.x * 256 + threadIdx.x;
  const int stride = gridDim.x * 256;
  // W1T[dt][hc][f] = W1[dt][f][hc]
  for (int idx = i; idx < kKS * kH * kF; idx += stride) {
    const int f  = idx & 255;
    const int hc = (idx >> 8) & 255;
    const int dt = idx >> 16;
    w1t[idx] = __float2bfloat16(W1[(dt * kF + f) * kH + hc]);
  }
  // W2T[o][dt*256+hc] = W2[dt][hc][o]
  for (int idx = i; idx < kOUT * kKS * kH; idx += stride) {
    const int k = idx % (kKS * kH);
    const int o = idx / (kKS * kH);
    w2t[idx] = __float2bfloat16(W2[k * kOUT + o]);
  }
}

// ---------------- kernel 2: fused gather+topk+conv1+conv2 ----------------
__global__ __launch_bounds__(256)
void fused_all(const int* __restrict__ node_ids,
               const int* __restrict__ neighbors,
               const float* __restrict__ feat,
               const bf16* __restrict__ w1t, const bf16* __restrict__ w2t,
               const float* __restrict__ b1, const float* __restrict__ b2,
               float* __restrict__ out)
{
  __shared__ bf16 smem[kBM * kXR * XPAD];  // 74304 B -> 2 blocks/CU
  bf16* xs = smem;
  bf16* hs = smem;

  const int tid  = threadIdx.x;
  const int wave = tid >> 6;
  const int lane = tid & 63;
  const int r = lane & 15;
  const int q = lane >> 4;
  const int bbase = blockIdx.x * kBM;
  const int f4 = lane << 2;

  // ================= gather + per-channel top-8 -> LDS (bf16) =================
  // One wave per batch element (4 sequential per wave). Lane owns 4 channels.
  // Rolling 8-deep register pipeline keeps 8x1KB row loads in flight.
  for (int bb = 0; bb < 4; ++bb) {
    const int bl = wave * 4 + bb;                 // local batch row 0..15
    const int b  = bbase + bl;
    const int myn = neighbors[(size_t)b * kNB + lane];
    const int nid = node_ids[b];
    const float4 nodev = *reinterpret_cast<const float4*>(feat + (size_t)nid * kF + f4);

    float tk[4][kK];
#pragma unroll
    for (int c = 0; c < 4; ++c)
#pragma unroll
      for (int k = 0; k < kK; ++k) tk[c][k] = -INFINITY;

    // branchless sorted insert of 4 channels (independent chains)
    auto ce4 = [&](const float4& v) {
      const float vv[4] = {v.x, v.y, v.z, v.w};
#pragma unroll
      for (int c = 0; c < 4; ++c) {
        tk[c][kK - 1] = fmaxf(tk[c][kK - 1], vv[c]);
#pragma unroll
        for (int k = kK - 1; k > 0; --k) {
          const float hi = fmaxf(tk[c][k - 1], tk[c][k]);
          const float lo = fminf(tk[c][k - 1], tk[c][k]);
          tk[c][k - 1] = hi;
          tk[c][k]     = lo;
        }
      }
    };

    float4 buf[8];
#pragma unroll
    for (int i = 0; i < 8; ++i) {
      const int rr = __builtin_amdgcn_readlane(myn, i);
      buf[i] = *reinterpret_cast<const float4*>(feat + (size_t)rr * kF + f4);
    }
    for (int g = 1; g < 8; ++g) {                 // groups of 8 rows
#pragma unroll
      for (int i = 0; i < 8; ++i) {
        const float4 v = buf[i];
        const int rr = __builtin_amdgcn_readlane(myn, g * 8 + i);
        buf[i] = *reinterpret_cast<const float4*>(feat + (size_t)rr * kF + f4);
        ce4(v);
      }
    }
#pragma unroll
    for (int i = 0; i < 8; ++i) ce4(buf[i]);

    bf16* xb = xs + (size_t)bl * kXR * XPAD + f4;
    {
      ushort4 s = {f2bf(nodev.x), f2bf(nodev.y), f2bf(nodev.z), f2bf(nodev.w)};
      *reinterpret_cast<ushort4*>(xb) = s;
    }
#pragma unroll
    for (int k = 0; k < kK; ++k) {
      ushort4 s = {f2bf(tk[0][k]), f2bf(tk[1][k]), f2bf(tk[2][k]), f2bf(tk[3][k])};
      *reinterpret_cast<ushort4*>(xb + (size_t)(1 + k) * XPAD) = s;
    }
  }
  __syncthreads();

  // ================= GEMM1: h[b][t][hc] = sum_dt,f x[b][t+dt][f]*W1[dt][f][hc] + b1 ==========
  const int ntb = wave * 64;
  f32x4 acc[kTO][4];
#pragma unroll
  for (int n = 0; n < 4; ++n) {
    const float bv = b1[ntb + n * 16 + r];
#pragma unroll
    for (int m = 0; m < kTO; ++m) acc[m][n] = (f32x4){bv, bv, bv, bv};
  }

  for (int kk = 0; kk < 8; ++kk) {
    short8 a[kXR];
#pragma unroll
    for (int rr = 0; rr < kXR; ++rr)
      a[rr] = *reinterpret_cast<const short8*>(&xs[(r * kXR + rr) * XPAD + kk * 32 + q * 8]);
#pragma unroll
    for (int dt = 0; dt < kKS; ++dt) {
      short8 bfr[4];
#pragma unroll
      for (int n = 0; n < 4; ++n)
        bfr[n] = *reinterpret_cast<const short8*>(
            &w1t[((size_t)(dt * kH + ntb + n * 16 + r)) * kF + kk * 32 + q * 8]);
#pragma unroll
      for (int m = 0; m < kTO; ++m)
#pragma unroll
        for (int n = 0; n < 4; ++n)
          acc[m][n] = __builtin_amdgcn_mfma_f32_16x16x32_bf16(a[m + dt], bfr[n], acc[m][n], 0, 0, 0);
    }
  }
  __syncthreads();  // all waves done reading xs; safe to overwrite with h

  // ---- write h (bf16) into LDS: hs[b][t*256 + hc]  (C/D: col=lane&15, row=q*4+j) ----
#pragma unroll
  for (int m = 0; m < kTO; ++m)
#pragma unroll
    for (int n = 0; n < 4; ++n)
#pragma unroll
      for (int j = 0; j < 4; ++j)
        hs[(q * 4 + j) * HPAD + m * kH + ntb + n * 16 + r] = __float2bfloat16(acc[m][n][j]);
  __syncthreads();

  // ================= GEMM2: out[b][o] = sum_k h[b][k]*W2T[o][k] + b2 =================
  const int ob = wave * 32;
  f32x4 acc2[2];
#pragma unroll
  for (int n = 0; n < 2; ++n) {
    const float bv = b2[ob + n * 16 + r];
    acc2[n] = (f32x4){bv, bv, bv, bv};
  }
  for (int ks = 0; ks < 40; ++ks) {
    short8 a2 = *reinterpret_cast<const short8*>(&hs[r * HPAD + ks * 32 + q * 8]);
#pragma unroll
    for (int n = 0; n < 2; ++n) {
      short8 b2f = *reinterpret_cast<const short8*>(
          &w2t[(size_t)(ob + n * 16 + r) * (kKS * kH) + ks * 32 + q * 8]);
      acc2[n] = __builtin_amdgcn_mfma_f32_16x16x32_bf16(a2, b2f, acc2[n], 0, 0, 0);
    }
  }
#pragma unroll
  for (int n = 0; n < 2; ++n)
#pragma unroll
    for (int j = 0; j < 4; ++j)
      out[(size_t)(bbase + q * 4 + j) * kOUT + ob + n * 16 + r] = acc2[n][j];
}

extern "C" void kernel_launch(void* const* d_in, const int* in_sizes, int n_in,
                              void* d_out, int out_size, void* d_ws, size_t ws_size,
                              hipStream_t stream) {
  const int*   node_ids  = (const int*)  d_in[0];
  const int*   neighbors = (const int*)  d_in[1];
  const float* feat      = (const float*)d_in[2];
  const float* W1        = (const float*)d_in[3];
  const float* b1        = (const float*)d_in[4];
  const float* W2        = (const float*)d_in[5];
  const float* b2        = (const float*)d_in[6];
  float* out = (float*)d_out;

  char* ws = (char*)d_ws;
  bf16* w1t = (bf16*)(ws + W1T_OFF);
  bf16* w2t = (bf16*)(ws + W2T_OFF);

  convert_weights<<<512, 256, 0, stream>>>(W1, W2, w1t, w2t);
  fused_all<<<kB / kBM, 256, 0, stream>>>(node_ids, neighbors, feat, w1t, w2t, b1, b2, out);
}

// Round 5
// 138.530 us; speedup vs baseline: 5.3968x; 1.0044x over previous
//
#include <hip/hip_runtime.h>
#include <hip/hip_bf16.h>

namespace {
constexpr int kB    = 8192;
constexpr int kNB   = 64;
constexpr int kF    = 256;
constexpr int kK    = 8;
constexpr int kKS   = 5;
constexpr int kH    = 256;
constexpr int kOUT  = 128;
constexpr int kXR   = 9;   // x rows (1 node + 8 topk)
constexpr int kTO   = 5;   // conv1 output positions
constexpr int kBM   = 16;  // batch rows per block

constexpr int XPAD = 258;   // r-stride = 9*129 dwords ≡ 9 (odd) mod 32 -> ≤2-way alias (free)
constexpr int HPAD = 1290;  // row stride 645 dwords ≡ 5 (odd) mod 32 -> ≤2-way alias (free)

// workspace layout (bytes)
constexpr size_t W1T_OFF = 0;                                   // bf16 [5][256(hc)][256(f)]
constexpr size_t W2T_OFF = W1T_OFF + (size_t)kKS * kH * kF * 2; // bf16 [128(o)][1280(k)]

typedef __attribute__((ext_vector_type(8))) short short8; // 8 bf16 (A/B frag)
typedef __attribute__((ext_vector_type(4))) float f32x4;  // C/D frag
}

using bf16 = __hip_bfloat16;

__device__ __forceinline__ unsigned short f2bf(float f) {
  bf16 h = __float2bfloat16(f);
  return *reinterpret_cast<unsigned short*>(&h);
}

// ---------------- kernel 1: weight convert/transpose to bf16 ----------------
__global__ void convert_weights(const float* __restrict__ W1,
                                const float* __restrict__ W2,
                                bf16* __restrict__ w1t, bf16* __restrict__ w2t)
{
  const int i = blockIdx.x * 256 + threadIdx.x;
  const int stride = gridDim.x * 256;
  // W1T[dt][hc][f] = W1[dt][f][hc]
  for (int idx = i; idx < kKS * kH * kF; idx += stride) {
    const int f  = idx & 255;
    const int hc = (idx >> 8) & 255;
    const int dt = idx >> 16;
    w1t[idx] = __float2bfloat16(W1[(dt * kF + f) * kH + hc]);
  }
  // W2T[o][dt*256+hc] = W2[dt][hc][o]
  for (int idx = i; idx < kOUT * kKS * kH; idx += stride) {
    const int k = idx % (kKS * kH);
    const int o = idx / (kKS * kH);
    w2t[idx] = __float2bfloat16(W2[k * kOUT + o]);
  }
}

// ---------------- kernel 2: fused gather+topk+conv1+conv2 ----------------
__global__ __launch_bounds__(256)
void fused_all(const int* __restrict__ node_ids,
               const int* __restrict__ neighbors,
               const float* __restrict__ feat,
               const bf16* __restrict__ w1t, const bf16* __restrict__ w2t,
               const float* __restrict__ b1, const float* __restrict__ b2,
               float* __restrict__ out)
{
  __shared__ bf16 smem[kBM * kXR * XPAD];  // 74304 B -> 2 blocks/CU
  bf16* xs = smem;
  bf16* hs = smem;

  const int tid  = threadIdx.x;
  const int wave = tid >> 6;
  const int lane = tid & 63;
  const int r = lane & 15;
  const int q = lane >> 4;
  const int bbase = blockIdx.x * kBM;
  const int f4 = lane << 2;

  // ================= gather + per-channel top-8 -> LDS (bf16) =================
  // One wave per batch element (4 sequential per wave). Lane owns 4 channels.
  // 16-deep rolling register pipeline keeps 16x1KB row loads in flight.
  // Prefetch all 4 neighbor-id words + node rows up front.
  int   myn4[4];
  float4 node4[4];
#pragma unroll
  for (int bb = 0; bb < 4; ++bb) {
    const int b = bbase + wave * 4 + bb;
    myn4[bb] = neighbors[(size_t)b * kNB + lane];
    node4[bb] = *reinterpret_cast<const float4*>(feat + (size_t)node_ids[b] * kF + f4);
  }

#pragma unroll
  for (int bb = 0; bb < 4; ++bb) {
    const int bl  = wave * 4 + bb;                 // local batch row 0..15
    const int myn = myn4[bb];

    float tk[4][kK];
#pragma unroll
    for (int c = 0; c < 4; ++c)
#pragma unroll
      for (int k = 0; k < kK; ++k) tk[c][k] = -INFINITY;

    // sorted insert via med3 network: 8 ops/channel, fully data-parallel.
    // t0' = max(t0,v); tk' = med3(t[k-1], t[k], v)  (descending list)
    auto ins4 = [&](const float4& v) {
      const float vv[4] = {v.x, v.y, v.z, v.w};
#pragma unroll
      for (int c = 0; c < 4; ++c) {
        float nt[kK];
        nt[0] = fmaxf(tk[c][0], vv[c]);
#pragma unroll
        for (int k = 1; k < kK; ++k)
          nt[k] = __builtin_amdgcn_fmed3f(tk[c][k - 1], tk[c][k], vv[c]);
#pragma unroll
        for (int k = 0; k < kK; ++k) tk[c][k] = nt[k];
      }
    };

    float4 buf[16];
#pragma unroll
    for (int i = 0; i < 16; ++i) {
      const int rr = __builtin_amdgcn_readlane(myn, i);
      buf[i] = *reinterpret_cast<const float4*>(feat + (size_t)rr * kF + f4);
    }
#pragma unroll
    for (int g = 1; g < 4; ++g) {                  // groups of 16 rows
#pragma unroll
      for (int i = 0; i < 16; ++i) {
        const float4 v = buf[i];
        const int rr = __builtin_amdgcn_readlane(myn, g * 16 + i);
        buf[i] = *reinterpret_cast<const float4*>(feat + (size_t)rr * kF + f4);
        ins4(v);
      }
    }
#pragma unroll
    for (int i = 0; i < 16; ++i) ins4(buf[i]);

    bf16* xb = xs + (size_t)bl * kXR * XPAD + f4;
    {
      ushort4 s = {f2bf(node4[bb].x), f2bf(node4[bb].y), f2bf(node4[bb].z), f2bf(node4[bb].w)};
      *reinterpret_cast<ushort4*>(xb) = s;
    }
#pragma unroll
    for (int k = 0; k < kK; ++k) {
      ushort4 s = {f2bf(tk[0][k]), f2bf(tk[1][k]), f2bf(tk[2][k]), f2bf(tk[3][k])};
      *reinterpret_cast<ushort4*>(xb + (size_t)(1 + k) * XPAD) = s;
    }
  }
  __syncthreads();

  // ================= GEMM1: h[b][t][hc] = sum_dt,f x[b][t+dt][f]*W1[dt][f][hc] + b1 ==========
  const int ntb = wave * 64;
  f32x4 acc[kTO][4];
#pragma unroll
  for (int n = 0; n < 4; ++n) {
    const float bv = b1[ntb + n * 16 + r];
#pragma unroll
    for (int m = 0; m < kTO; ++m) acc[m][n] = (f32x4){bv, bv, bv, bv};
  }

  for (int kk = 0; kk < 8; ++kk) {
    short8 a[kXR];
#pragma unroll
    for (int rr = 0; rr < kXR; ++rr)
      a[rr] = *reinterpret_cast<const short8*>(&xs[(r * kXR + rr) * XPAD + kk * 32 + q * 8]);
#pragma unroll
    for (int dt = 0; dt < kKS; ++dt) {
      short8 bfr[4];
#pragma unroll
      for (int n = 0; n < 4; ++n)
        bfr[n] = *reinterpret_cast<const short8*>(
            &w1t[((size_t)(dt * kH + ntb + n * 16 + r)) * kF + kk * 32 + q * 8]);
#pragma unroll
      for (int m = 0; m < kTO; ++m)
#pragma unroll
        for (int n = 0; n < 4; ++n)
          acc[m][n] = __builtin_amdgcn_mfma_f32_16x16x32_bf16(a[m + dt], bfr[n], acc[m][n], 0, 0, 0);
    }
  }
  __syncthreads();  // all waves done reading xs; safe to overwrite with h

  // ---- write h (bf16) into LDS: hs[b][t*256 + hc]  (C/D: col=lane&15, row=q*4+j) ----
#pragma unroll
  for (int m = 0; m < kTO; ++m)
#pragma unroll
    for (int n = 0; n < 4; ++n)
#pragma unroll
      for (int j = 0; j < 4; ++j)
        hs[(q * 4 + j) * HPAD + m * kH + ntb + n * 16 + r] = __float2bfloat16(acc[m][n][j]);
  __syncthreads();

  // ================= GEMM2: out[b][o] = sum_k h[b][k]*W2T[o][k] + b2 =================
  const int ob = wave * 32;
  f32x4 acc2[2];
#pragma unroll
  for (int n = 0; n < 2; ++n) {
    const float bv = b2[ob + n * 16 + r];
    acc2[n] = (f32x4){bv, bv, bv, bv};
  }
  for (int ks = 0; ks < 40; ++ks) {
    short8 a2 = *reinterpret_cast<const short8*>(&hs[r * HPAD + ks * 32 + q * 8]);
#pragma unroll
    for (int n = 0; n < 2; ++n) {
      short8 b2f = *reinterpret_cast<const short8*>(
          &w2t[(size_t)(ob + n * 16 + r) * (kKS * kH) + ks * 32 + q * 8]);
      acc2[n] = __builtin_amdgcn_mfma_f32_16x16x32_bf16(a2, b2f, acc2[n], 0, 0, 0);
    }
  }
#pragma unroll
  for (int n = 0; n < 2; ++n)
#pragma unroll
    for (int j = 0; j < 4; ++j)
      out[(size_t)(bbase + q * 4 + j) * kOUT + ob + n * 16 + r] = acc2[n][j];
}

extern "C" void kernel_launch(void* const* d_in, const int* in_sizes, int n_in,
                              void* d_out, int out_size, void* d_ws, size_t ws_size,
                              hipStream_t stream) {
  const int*   node_ids  = (const int*)  d_in[0];
  const int*   neighbors = (const int*)  d_in[1];
  const float* feat      = (const float*)d_in[2];
  const float* W1        = (const float*)d_in[3];
  const float* b1        = (const float*)d_in[4];
  const float* W2        = (const float*)d_in[5];
  const float* b2        = (const float*)d_in[6];
  float* out = (float*)d_out;

  char* ws = (char*)d_ws;
  bf16* w1t = (bf16*)(ws + W1T_OFF);
  bf16* w2t = (bf16*)(ws + W2T_OFF);

  convert_weights<<<512, 256, 0, stream>>>(W1, W2, w1t, w2t);
  fused_all<<<kB / kBM, 256, 0, stream>>>(node_ids, neighbors, feat, w1t, w2t, b1, b2, out);
}